// Round 1
// baseline (755.884 us; speedup 1.0000x reference)
//
#include <hip/hip_runtime.h>
#include <math.h>

// ---------------------------------------------------------------------------
// PseqStepV3: 3-layer TransformerConv (heads=1) on N=50000 nodes, E=800000
// edges, D=64.  Strategy:
//   once/call: detect edge_index dtype (int64 vs int32), build CSR by dst
//   per layer: fused q/k/v/s GEMM -> edge scores (written in CSR order)
//              -> node-parallel segment softmax + weighted v-gather + epilogue
// No float atomics anywhere; aggregation is wave-per-node, lane-per-channel.
// ---------------------------------------------------------------------------

#define D64 64

// ---- edge_index format detection: int64 rows have zero high words ----------
__global__ void detect_fmt(const int* __restrict__ ei, int nchecks, int* flag) {
    int t = blockIdx.x * blockDim.x + threadIdx.x;
    int acc = 0;
    for (int i = t; i < nchecks; i += blockDim.x * gridDim.x)
        acc |= ei[2 * i + 1];
    if (acc) atomicOr(flag, 1);   // nonzero => plain int32 layout
}

__device__ __forceinline__ int load_src(const int* ei, int e, int E, int is64) {
    return is64 ? ei[2 * e] : ei[e];
}
__device__ __forceinline__ int load_dst(const int* ei, int e, int E, int is64) {
    return is64 ? ei[2 * E + 2 * e] : ei[E + e];
}

// ---- CSR build -------------------------------------------------------------
__global__ void hist_dst(const int* __restrict__ ei, int* __restrict__ counts,
                         int E, const int* __restrict__ flag) {
    int e = blockIdx.x * blockDim.x + threadIdx.x;
    if (e >= E) return;
    int is64 = (*flag == 0);
    atomicAdd(&counts[load_dst(ei, e, E, is64)], 1);
}

__global__ void scan_offsets(const int* __restrict__ counts, int* __restrict__ offsets,
                             int* __restrict__ nxt, int n) {
    __shared__ int buf[1024];
    __shared__ int carry_s;
    int tid = threadIdx.x;
    if (tid == 0) { carry_s = 0; offsets[0] = 0; }
    __syncthreads();
    for (int base = 0; base < n; base += 1024) {
        int i = base + tid;
        int val = (i < n) ? counts[i] : 0;
        buf[tid] = val;
        __syncthreads();
        for (int off = 1; off < 1024; off <<= 1) {
            int t = (tid >= off) ? buf[tid - off] : 0;
            __syncthreads();
            buf[tid] += t;
            __syncthreads();
        }
        int incl = buf[tid];
        int carry = carry_s;
        if (i < n) {
            offsets[i + 1] = carry + incl;       // inclusive end
            nxt[i]         = carry + incl - val; // exclusive start (scatter cursor)
        }
        int total = buf[1023];
        __syncthreads();
        if (tid == 0) carry_s += total;
        __syncthreads();
    }
}

__global__ void scatter_csr(const int* __restrict__ ei, int* __restrict__ nxt,
                            int* __restrict__ csr_pos, int* __restrict__ csr_src,
                            int E, const int* __restrict__ flag) {
    int e = blockIdx.x * blockDim.x + threadIdx.x;
    if (e >= E) return;
    int is64 = (*flag == 0);
    int s = load_src(ei, e, E, is64);
    int d = load_dst(ei, e, E, is64);
    int pos = atomicAdd(&nxt[d], 1);
    csr_pos[e] = pos;
    csr_src[pos] = s;
}

// ---- fused q/k/v/s GEMM: out[r][d] = b[d] + sum_c x[r][c] * W[c][d] --------
__launch_bounds__(256, 2)
__global__ void gemm_qkvs(const float* __restrict__ x,
                          const float* __restrict__ Wq, const float* __restrict__ bq,
                          const float* __restrict__ Wk, const float* __restrict__ bk,
                          const float* __restrict__ Wv, const float* __restrict__ bv,
                          const float* __restrict__ Ws, const float* __restrict__ bs,
                          float* __restrict__ q, float* __restrict__ k,
                          float* __restrict__ v, float* __restrict__ s, int n) {
    // W4[c][lane][4] : interleave the 4 matrices -> one ds_read_b128 per k-step
    __shared__ float W4[64 * 256];  // 64 KiB
    int tid = threadIdx.x;
    for (int i = tid; i < 64 * 64; i += 256) {
        int c = i >> 6, l = i & 63;
        float* p = &W4[c * 256 + l * 4];
        p[0] = Wq[i]; p[1] = Wk[i]; p[2] = Wv[i]; p[3] = Ws[i];
    }
    __syncthreads();

    int row0  = blockIdx.x * 64;
    int nrows = n - row0; if (nrows > 64) nrows = 64;
    int wave = tid >> 6, lane = tid & 63;
    float bqv = bq[lane], bkv = bk[lane], bvv = bv[lane], bsv = bs[lane];

    for (int g = 0; g < 4; ++g) {
        int rl = wave * 16 + g * 4;          // local row base (0..63)
        int rbase = row0 + rl;
        float xv0 = (rl + 0 < nrows) ? x[(size_t)(rbase + 0) * D64 + lane] : 0.f;
        float xv1 = (rl + 1 < nrows) ? x[(size_t)(rbase + 1) * D64 + lane] : 0.f;
        float xv2 = (rl + 2 < nrows) ? x[(size_t)(rbase + 2) * D64 + lane] : 0.f;
        float xv3 = (rl + 3 < nrows) ? x[(size_t)(rbase + 3) * D64 + lane] : 0.f;
        float aq0 = bqv, aq1 = bqv, aq2 = bqv, aq3 = bqv;
        float ak0 = bkv, ak1 = bkv, ak2 = bkv, ak3 = bkv;
        float av0 = bvv, av1 = bvv, av2 = bvv, av3 = bvv;
        float as0 = bsv, as1 = bsv, as2 = bsv, as3 = bsv;
#pragma unroll 16
        for (int c = 0; c < 64; ++c) {
            const float4 w = *(const float4*)&W4[c * 256 + lane * 4];
            float x0 = __shfl(xv0, c);
            float x1 = __shfl(xv1, c);
            float x2 = __shfl(xv2, c);
            float x3 = __shfl(xv3, c);
            aq0 += x0 * w.x; aq1 += x1 * w.x; aq2 += x2 * w.x; aq3 += x3 * w.x;
            ak0 += x0 * w.y; ak1 += x1 * w.y; ak2 += x2 * w.y; ak3 += x3 * w.y;
            av0 += x0 * w.z; av1 += x1 * w.z; av2 += x2 * w.z; av3 += x3 * w.z;
            as0 += x0 * w.w; as1 += x1 * w.w; as2 += x2 * w.w; as3 += x3 * w.w;
        }
        float AQ[4] = {aq0, aq1, aq2, aq3};
        float AK[4] = {ak0, ak1, ak2, ak3};
        float AV[4] = {av0, av1, av2, av3};
        float AS[4] = {as0, as1, as2, as3};
#pragma unroll
        for (int i = 0; i < 4; ++i) {
            if (rl + i < nrows) {
                size_t o = (size_t)(rbase + i) * D64 + lane;
                q[o] = AQ[i]; k[o] = AK[i]; v[o] = AV[i]; s[o] = AS[i];
            }
        }
    }
}

// ---- per-edge attention logits, written in CSR order -----------------------
__launch_bounds__(256)
__global__ void edge_scores(const float* __restrict__ q, const float* __restrict__ k,
                            const int* __restrict__ ei, const int* __restrict__ csr_pos,
                            float* __restrict__ scores, int E,
                            const int* __restrict__ flag) {
    int t = blockIdx.x * 256 + threadIdx.x;
    int e = t >> 4, l16 = t & 15;
    if (e >= E) return;
    int is64 = (*flag == 0);
    int sidx = load_src(ei, e, E, is64);
    int didx = load_dst(ei, e, E, is64);
    const float4 qv = *(const float4*)(q + (size_t)didx * D64 + l16 * 4);
    const float4 kv = *(const float4*)(k + (size_t)sidx * D64 + l16 * 4);
    float p = qv.x * kv.x + qv.y * kv.y + qv.z * kv.z + qv.w * kv.w;
    p += __shfl_xor(p, 1, 16);
    p += __shfl_xor(p, 2, 16);
    p += __shfl_xor(p, 4, 16);
    p += __shfl_xor(p, 8, 16);
    if (l16 == 0) scores[csr_pos[e]] = p * 0.125f;  // 1/sqrt(64)
}

// ---- node-parallel segment softmax + weighted v gather + epilogue ----------
// MODE 1: out = silu(t)            (t = agg/denom + skip)
// MODE 2: out = silu(t + xin)      (residual, in-place safe)
// MODE 3: out = t + 0.1*z          (final drift + noise)
template <int MODE>
__launch_bounds__(256)
__global__ void node_agg(const float* __restrict__ scores, const int* __restrict__ csr_src,
                         const int* __restrict__ offsets, const float* __restrict__ v,
                         const float* __restrict__ sbuf, const float* __restrict__ xin,
                         const float* __restrict__ z, float* __restrict__ out, int n) {
    int node = blockIdx.x * 4 + (threadIdx.x >> 6);
    int lane = threadIdx.x & 63;
    if (node >= n) return;
    int start = offsets[node], end = offsets[node + 1];
    float t;
    if (end > start) {
        float m = -3.0e38f;
        for (int base = start; base < end; base += 64) {
            int i = base + lane;
            float sc = (i < end) ? scores[i] : -3.0e38f;
            m = fmaxf(m, sc);
        }
#pragma unroll
        for (int off = 32; off; off >>= 1) m = fmaxf(m, __shfl_xor(m, off));

        float acc = 0.f, denom = 0.f;
        for (int base = start; base < end; base += 64) {
            int i = base + lane;
            int cnt = end - base; if (cnt > 64) cnt = 64;
            float ex = 0.f;
            int sj = 0;
            if (i < end) {
                ex = __expf(scores[i] - m);
                sj = csr_src[i];
            }
            denom += ex;
            for (int j = 0; j < cnt; ++j) {
                float exj = __shfl(ex, j);
                int srcj  = __shfl(sj, j);
                acc += exj * v[(size_t)srcj * D64 + lane];
            }
        }
#pragma unroll
        for (int off = 32; off; off >>= 1) denom += __shfl_xor(denom, off);
        t = acc / denom + sbuf[(size_t)node * D64 + lane];
    } else {
        t = sbuf[(size_t)node * D64 + lane];   // isolated node: agg = 0
    }
    if (MODE == 1) {
        t = t / (1.f + __expf(-t));
    } else if (MODE == 2) {
        float u = t + xin[(size_t)node * D64 + lane];
        t = u / (1.f + __expf(-u));
    } else {
        t = t + 0.1f * z[(size_t)node * D64 + lane];
    }
    out[(size_t)node * D64 + lane] = t;
}

// ---------------------------------------------------------------------------
extern "C" void kernel_launch(void* const* d_in, const int* in_sizes, int n_in,
                              void* d_out, int out_size, void* d_ws, size_t ws_size,
                              hipStream_t stream) {
    const float* x = (const float*)d_in[0];
    const int* ei  = (const int*)d_in[1];
    const float* z = (const float*)d_in[2];
    const float* W[3][4];
    const float* B[3][4];
    for (int l = 0; l < 3; ++l)
        for (int m = 0; m < 4; ++m) {
            W[l][m] = (const float*)d_in[3 + l * 8 + m * 2];
            B[l][m] = (const float*)d_in[3 + l * 8 + m * 2 + 1];
        }
    int N = in_sizes[0] / D64;
    int E = in_sizes[1] / 2;
    size_t ND = (size_t)N * D64;

    char* p = (char*)d_ws;
    auto alloc = [&](size_t bytes) {
        char* r = p;
        p += (bytes + 255) & ~(size_t)255;
        return r;
    };
    float* q       = (float*)alloc(ND * 4);
    float* k       = (float*)alloc(ND * 4);
    float* v       = (float*)alloc(ND * 4);
    float* sb      = (float*)alloc(ND * 4);
    float* hA      = (float*)alloc(ND * 4);
    float* scores  = (float*)alloc((size_t)E * 4);
    int* csr_src   = (int*)alloc((size_t)E * 4);
    int* csr_pos   = (int*)alloc((size_t)E * 4);
    int* offsets   = (int*)alloc((size_t)(N + 1) * 4);
    int* counts    = (int*)alloc((size_t)N * 4);
    int* nxt       = (int*)alloc((size_t)N * 4);
    int* flag      = (int*)alloc(4);
    float* outp    = (float*)d_out;

    hipMemsetAsync(flag, 0, 4, stream);
    hipMemsetAsync(counts, 0, (size_t)N * 4, stream);
    int nchecks = E < 4096 ? E : 4096;
    detect_fmt<<<1, 256, 0, stream>>>(ei, nchecks, flag);
    hist_dst<<<(E + 255) / 256, 256, 0, stream>>>(ei, counts, E, flag);
    scan_offsets<<<1, 1024, 0, stream>>>(counts, offsets, nxt, N);
    scatter_csr<<<(E + 255) / 256, 256, 0, stream>>>(ei, nxt, csr_pos, csr_src, E, flag);

    int gemm_grid = (N + 63) / 64;
    int edge_grid = (int)(((size_t)E * 16 + 255) / 256);
    int node_grid = (N + 3) / 4;

    // layer 1: x -> hA, silu
    gemm_qkvs<<<gemm_grid, 256, 0, stream>>>(x, W[0][0], B[0][0], W[0][1], B[0][1],
                                             W[0][2], B[0][2], W[0][3], B[0][3],
                                             q, k, v, sb, N);
    edge_scores<<<edge_grid, 256, 0, stream>>>(q, k, ei, csr_pos, scores, E, flag);
    node_agg<1><<<node_grid, 256, 0, stream>>>(scores, csr_src, offsets, v, sb,
                                               nullptr, nullptr, hA, N);
    // layer 2: hA -> hA (residual + silu), in-place safe (elementwise epilogue)
    gemm_qkvs<<<gemm_grid, 256, 0, stream>>>(hA, W[1][0], B[1][0], W[1][1], B[1][1],
                                             W[1][2], B[1][2], W[1][3], B[1][3],
                                             q, k, v, sb, N);
    edge_scores<<<edge_grid, 256, 0, stream>>>(q, k, ei, csr_pos, scores, E, flag);
    node_agg<2><<<node_grid, 256, 0, stream>>>(scores, csr_src, offsets, v, sb,
                                               hA, nullptr, hA, N);
    // layer 3: hA -> out, + 0.1*z
    gemm_qkvs<<<gemm_grid, 256, 0, stream>>>(hA, W[2][0], B[2][0], W[2][1], B[2][1],
                                             W[2][2], B[2][2], W[2][3], B[2][3],
                                             q, k, v, sb, N);
    edge_scores<<<edge_grid, 256, 0, stream>>>(q, k, ei, csr_pos, scores, E, flag);
    node_agg<3><<<node_grid, 256, 0, stream>>>(scores, csr_src, offsets, v, sb,
                                               nullptr, z, outp, N);
}

// Round 2
// 613.532 us; speedup vs baseline: 1.2320x; 1.2320x over previous
//
#include <hip/hip_runtime.h>
#include <math.h>

// ---------------------------------------------------------------------------
// PseqStepV3: 3-layer TransformerConv (heads=1) on N=50000 nodes, E=800000
// edges, D=64.
//   once/call: detect edge_index dtype (int64 vs int32), build CSR by dst
//              (multi-block scan, ~10us vs 95us single-block in R1)
//   per layer: fused q/k/v/s GEMM -> edge scores (CSR order)
//              -> node-parallel segment softmax + weighted v-gather + epilogue
// node_agg: 4 edge-groups x 16 lanes x float4 channels (R1 was serial j-loop).
// ---------------------------------------------------------------------------

#define D64 64

// ---- edge_index format detection: int64 rows have zero high words ----------
__global__ void detect_fmt(const int* __restrict__ ei, int nchecks, int* flag) {
    int t = blockIdx.x * blockDim.x + threadIdx.x;
    int acc = 0;
    for (int i = t; i < nchecks; i += blockDim.x * gridDim.x)
        acc |= ei[2 * i + 1];
    if (acc) atomicOr(flag, 1);   // nonzero => plain int32 layout
}

__device__ __forceinline__ int load_src(const int* ei, int e, int E, int is64) {
    return is64 ? ei[2 * e] : ei[e];
}
__device__ __forceinline__ int load_dst(const int* ei, int e, int E, int is64) {
    return is64 ? ei[2 * E + 2 * e] : ei[E + e];
}

// ---- CSR build -------------------------------------------------------------
__global__ void hist_dst(const int* __restrict__ ei, int* __restrict__ counts,
                         int E, const int* __restrict__ flag) {
    int e = blockIdx.x * blockDim.x + threadIdx.x;
    if (e >= E) return;
    int is64 = (*flag == 0);
    atomicAdd(&counts[load_dst(ei, e, E, is64)], 1);
}

// multi-block exclusive-scan, stage 1: per-block (1024 elems) inclusive scan
__global__ void scan_blocks(const int* __restrict__ counts, int* __restrict__ partial,
                            int* __restrict__ blockSums, int n) {
    int tid = threadIdx.x;                 // 256
    int base = blockIdx.x * 1024 + tid * 4;
    int4 c = make_int4(0, 0, 0, 0);
    if (base + 3 < n) c = *(const int4*)&counts[base];
    else {
        if (base + 0 < n) c.x = counts[base + 0];
        if (base + 1 < n) c.y = counts[base + 1];
        if (base + 2 < n) c.z = counts[base + 2];
        if (base + 3 < n) c.w = counts[base + 3];
    }
    int s1 = c.x, s2 = s1 + c.y, s3 = s2 + c.z, s4 = s3 + c.w;
    int lane = tid & 63, wave = tid >> 6;
    int v = s4;
#pragma unroll
    for (int off = 1; off < 64; off <<= 1) {
        int t = __shfl_up(v, off);
        if (lane >= off) v += t;
    }
    __shared__ int wsum[4];
    if (lane == 63) wsum[wave] = v;
    __syncthreads();
    int wpre = 0;
    for (int w = 0; w < wave; ++w) wpre += wsum[w];
    int pre = wpre + v - s4;               // exclusive prefix of this thread's 4
    if (base + 0 < n) partial[base + 0] = pre + s1;
    if (base + 1 < n) partial[base + 1] = pre + s2;
    if (base + 2 < n) partial[base + 2] = pre + s3;
    if (base + 3 < n) partial[base + 3] = pre + s4;
    if (tid == 0) { /* nothing */ }
    if (tid == 255) blockSums[blockIdx.x] = wsum[0] + wsum[1] + wsum[2] + wsum[3];
}

// stage 2: one wave scans the block sums (49 of them), exclusive
__global__ void scan_sums(int* __restrict__ bs, int nb) {
    int lane = threadIdx.x;                // 64
    int carry = 0;
    for (int b0 = 0; b0 < nb; b0 += 64) {
        int i = b0 + lane;
        int val = (i < nb) ? bs[i] : 0;
        int v = val;
#pragma unroll
        for (int off = 1; off < 64; off <<= 1) {
            int t = __shfl_up(v, off);
            if (lane >= off) v += t;
        }
        if (i < nb) bs[i] = carry + v - val;   // exclusive
        carry += __shfl(v, 63);
    }
}

// stage 3: add block prefix, emit offsets[] (inclusive end) and nxt[] cursors
__global__ void scan_final(const int* __restrict__ counts, const int* __restrict__ partial,
                           const int* __restrict__ bs, int* __restrict__ offsets,
                           int* __restrict__ nxt, int n) {
    int i = blockIdx.x * 256 + threadIdx.x;
    if (i >= n) return;
    int inc = partial[i] + bs[i >> 10];
    offsets[i + 1] = inc;
    nxt[i] = inc - counts[i];
    if (i == 0) offsets[0] = 0;
}

__global__ void scatter_csr(const int* __restrict__ ei, int* __restrict__ nxt,
                            int* __restrict__ csr_pos, int* __restrict__ csr_src,
                            int E, const int* __restrict__ flag) {
    int e = blockIdx.x * blockDim.x + threadIdx.x;
    if (e >= E) return;
    int is64 = (*flag == 0);
    int s = load_src(ei, e, E, is64);
    int d = load_dst(ei, e, E, is64);
    int pos = atomicAdd(&nxt[d], 1);
    csr_pos[e] = pos;
    csr_src[pos] = s;
}

// ---- fused q/k/v/s GEMM: out[r][d] = b[d] + sum_c x[r][c] * W[c][d] --------
__launch_bounds__(256, 2)
__global__ void gemm_qkvs(const float* __restrict__ x,
                          const float* __restrict__ Wq, const float* __restrict__ bq,
                          const float* __restrict__ Wk, const float* __restrict__ bk,
                          const float* __restrict__ Wv, const float* __restrict__ bv,
                          const float* __restrict__ Ws, const float* __restrict__ bs,
                          float* __restrict__ q, float* __restrict__ k,
                          float* __restrict__ v, float* __restrict__ s, int n) {
    __shared__ float W4[64 * 256];  // 64 KiB: W4[c][lane][4] interleaved
    int tid = threadIdx.x;
    for (int i = tid; i < 64 * 64; i += 256) {
        int c = i >> 6, l = i & 63;
        float* p = &W4[c * 256 + l * 4];
        p[0] = Wq[i]; p[1] = Wk[i]; p[2] = Wv[i]; p[3] = Ws[i];
    }
    __syncthreads();

    int row0  = blockIdx.x * 64;
    int nrows = n - row0; if (nrows > 64) nrows = 64;
    int wave = tid >> 6, lane = tid & 63;
    float bqv = bq[lane], bkv = bk[lane], bvv = bv[lane], bsv = bs[lane];

    for (int g = 0; g < 4; ++g) {
        int rl = wave * 16 + g * 4;
        int rbase = row0 + rl;
        float xv0 = (rl + 0 < nrows) ? x[(size_t)(rbase + 0) * D64 + lane] : 0.f;
        float xv1 = (rl + 1 < nrows) ? x[(size_t)(rbase + 1) * D64 + lane] : 0.f;
        float xv2 = (rl + 2 < nrows) ? x[(size_t)(rbase + 2) * D64 + lane] : 0.f;
        float xv3 = (rl + 3 < nrows) ? x[(size_t)(rbase + 3) * D64 + lane] : 0.f;
        float aq0 = bqv, aq1 = bqv, aq2 = bqv, aq3 = bqv;
        float ak0 = bkv, ak1 = bkv, ak2 = bkv, ak3 = bkv;
        float av0 = bvv, av1 = bvv, av2 = bvv, av3 = bvv;
        float as0 = bsv, as1 = bsv, as2 = bsv, as3 = bsv;
#pragma unroll 16
        for (int c = 0; c < 64; ++c) {
            const float4 w = *(const float4*)&W4[c * 256 + lane * 4];
            float x0 = __shfl(xv0, c);
            float x1 = __shfl(xv1, c);
            float x2 = __shfl(xv2, c);
            float x3 = __shfl(xv3, c);
            aq0 += x0 * w.x; aq1 += x1 * w.x; aq2 += x2 * w.x; aq3 += x3 * w.x;
            ak0 += x0 * w.y; ak1 += x1 * w.y; ak2 += x2 * w.y; ak3 += x3 * w.y;
            av0 += x0 * w.z; av1 += x1 * w.z; av2 += x2 * w.z; av3 += x3 * w.z;
            as0 += x0 * w.w; as1 += x1 * w.w; as2 += x2 * w.w; as3 += x3 * w.w;
        }
        float AQ[4] = {aq0, aq1, aq2, aq3};
        float AK[4] = {ak0, ak1, ak2, ak3};
        float AV[4] = {av0, av1, av2, av3};
        float AS[4] = {as0, as1, as2, as3};
#pragma unroll
        for (int i = 0; i < 4; ++i) {
            if (rl + i < nrows) {
                size_t o = (size_t)(rbase + i) * D64 + lane;
                q[o] = AQ[i]; k[o] = AK[i]; v[o] = AV[i]; s[o] = AS[i];
            }
        }
    }
}

// ---- per-edge attention logits, written in CSR order -----------------------
__launch_bounds__(256)
__global__ void edge_scores(const float* __restrict__ q, const float* __restrict__ k,
                            const int* __restrict__ ei, const int* __restrict__ csr_pos,
                            float* __restrict__ scores, int E,
                            const int* __restrict__ flag) {
    int t = blockIdx.x * 256 + threadIdx.x;
    int e = t >> 4, l16 = t & 15;
    if (e >= E) return;
    int is64 = (*flag == 0);
    int sidx = load_src(ei, e, E, is64);
    int didx = load_dst(ei, e, E, is64);
    const float4 qv = *(const float4*)(q + (size_t)didx * D64 + l16 * 4);
    const float4 kv = *(const float4*)(k + (size_t)sidx * D64 + l16 * 4);
    float p = qv.x * kv.x + qv.y * kv.y + qv.z * kv.z + qv.w * kv.w;
    p += __shfl_xor(p, 1, 16);
    p += __shfl_xor(p, 2, 16);
    p += __shfl_xor(p, 4, 16);
    p += __shfl_xor(p, 8, 16);
    if (l16 == 0) scores[csr_pos[e]] = p * 0.125f;  // 1/sqrt(64)
}

// ---- node-parallel segment softmax + weighted v gather + epilogue ----------
// Wave layout: 4 groups x 16 lanes. Group owns one edge/iter; lane l16 owns
// channels [l16*4, l16*4+4) as float4. Cross-group shfl_xor(16,32) at end.
// MODE 1: out = silu(t)        MODE 2: out = silu(t + xin)   MODE 3: t + 0.1*z
template <int MODE>
__launch_bounds__(256)
__global__ void node_agg(const float* __restrict__ scores, const int* __restrict__ csr_src,
                         const int* __restrict__ offsets, const float* __restrict__ v,
                         const float* __restrict__ sbuf, const float* __restrict__ xin,
                         const float* __restrict__ z, float* __restrict__ out, int n) {
    int node = blockIdx.x * 4 + (threadIdx.x >> 6);
    if (node >= n) return;
    int lane = threadIdx.x & 63;
    int grp = lane >> 4, l16 = lane & 15;
    int start = offsets[node], end = offsets[node + 1];
    size_t co = (size_t)node * D64 + l16 * 4;
    float4 t = *(const float4*)(sbuf + co);   // skip term
    if (end > start) {
        float m = -3.0e38f;
        for (int i = start + lane; i < end; i += 64)
            m = fmaxf(m, scores[i]);
#pragma unroll
        for (int off = 32; off; off >>= 1) m = fmaxf(m, __shfl_xor(m, off));

        float denom = 0.f;
        for (int i = start + lane; i < end; i += 64)
            denom += __expf(scores[i] - m);
#pragma unroll
        for (int off = 32; off; off >>= 1) denom += __shfl_xor(denom, off);

        float4 acc = make_float4(0.f, 0.f, 0.f, 0.f);
        for (int i = start + grp; i < end; i += 4) {
            float ex = __expf(scores[i] - m);
            int sj = csr_src[i];
            const float4 vv = *(const float4*)(v + (size_t)sj * D64 + l16 * 4);
            acc.x += ex * vv.x; acc.y += ex * vv.y;
            acc.z += ex * vv.z; acc.w += ex * vv.w;
        }
#pragma unroll
        for (int off = 16; off <= 32; off <<= 1) {
            acc.x += __shfl_xor(acc.x, off);
            acc.y += __shfl_xor(acc.y, off);
            acc.z += __shfl_xor(acc.z, off);
            acc.w += __shfl_xor(acc.w, off);
        }
        float inv = 1.f / denom;
        t.x += acc.x * inv; t.y += acc.y * inv;
        t.z += acc.z * inv; t.w += acc.w * inv;
    }
    if (MODE == 1) {
        t.x = t.x / (1.f + __expf(-t.x));
        t.y = t.y / (1.f + __expf(-t.y));
        t.z = t.z / (1.f + __expf(-t.z));
        t.w = t.w / (1.f + __expf(-t.w));
    } else if (MODE == 2) {
        const float4 xi = *(const float4*)(xin + co);
        float ux = t.x + xi.x, uy = t.y + xi.y, uz = t.z + xi.z, uw = t.w + xi.w;
        t.x = ux / (1.f + __expf(-ux));
        t.y = uy / (1.f + __expf(-uy));
        t.z = uz / (1.f + __expf(-uz));
        t.w = uw / (1.f + __expf(-uw));
    } else {
        const float4 zi = *(const float4*)(z + co);
        t.x += 0.1f * zi.x; t.y += 0.1f * zi.y;
        t.z += 0.1f * zi.z; t.w += 0.1f * zi.w;
    }
    if (grp == 0) *(float4*)(out + co) = t;
}

// ---------------------------------------------------------------------------
extern "C" void kernel_launch(void* const* d_in, const int* in_sizes, int n_in,
                              void* d_out, int out_size, void* d_ws, size_t ws_size,
                              hipStream_t stream) {
    const float* x = (const float*)d_in[0];
    const int* ei  = (const int*)d_in[1];
    const float* z = (const float*)d_in[2];
    const float* W[3][4];
    const float* B[3][4];
    for (int l = 0; l < 3; ++l)
        for (int m = 0; m < 4; ++m) {
            W[l][m] = (const float*)d_in[3 + l * 8 + m * 2];
            B[l][m] = (const float*)d_in[3 + l * 8 + m * 2 + 1];
        }
    int N = in_sizes[0] / D64;
    int E = in_sizes[1] / 2;
    size_t ND = (size_t)N * D64;

    char* p = (char*)d_ws;
    auto alloc = [&](size_t bytes) {
        char* r = p;
        p += (bytes + 255) & ~(size_t)255;
        return r;
    };
    float* q       = (float*)alloc(ND * 4);
    float* k       = (float*)alloc(ND * 4);
    float* v       = (float*)alloc(ND * 4);
    float* sb      = (float*)alloc(ND * 4);
    float* hA      = (float*)alloc(ND * 4);
    float* scores  = (float*)alloc((size_t)E * 4);
    int* csr_src   = (int*)alloc((size_t)E * 4);
    int* csr_pos   = (int*)alloc((size_t)E * 4);
    int* offsets   = (int*)alloc((size_t)(N + 1) * 4);
    int* counts    = (int*)alloc((size_t)N * 4);
    int* nxt       = (int*)alloc((size_t)N * 4);
    int* partial   = (int*)alloc((size_t)N * 4);
    int* blockSums = (int*)alloc(4096);
    int* flag      = (int*)alloc(4);
    float* outp    = (float*)d_out;

    hipMemsetAsync(flag, 0, 4, stream);
    hipMemsetAsync(counts, 0, (size_t)N * 4, stream);
    int nchecks = E < 4096 ? E : 4096;
    detect_fmt<<<1, 256, 0, stream>>>(ei, nchecks, flag);
    hist_dst<<<(E + 255) / 256, 256, 0, stream>>>(ei, counts, E, flag);
    int nb = (N + 1023) / 1024;
    scan_blocks<<<nb, 256, 0, stream>>>(counts, partial, blockSums, N);
    scan_sums<<<1, 64, 0, stream>>>(blockSums, nb);
    scan_final<<<(N + 255) / 256, 256, 0, stream>>>(counts, partial, blockSums,
                                                    offsets, nxt, N);
    scatter_csr<<<(E + 255) / 256, 256, 0, stream>>>(ei, nxt, csr_pos, csr_src, E, flag);

    int gemm_grid = (N + 63) / 64;
    int edge_grid = (int)(((size_t)E * 16 + 255) / 256);
    int node_grid = (N + 3) / 4;

    // layer 1: x -> hA, silu
    gemm_qkvs<<<gemm_grid, 256, 0, stream>>>(x, W[0][0], B[0][0], W[0][1], B[0][1],
                                             W[0][2], B[0][2], W[0][3], B[0][3],
                                             q, k, v, sb, N);
    edge_scores<<<edge_grid, 256, 0, stream>>>(q, k, ei, csr_pos, scores, E, flag);
    node_agg<1><<<node_grid, 256, 0, stream>>>(scores, csr_src, offsets, v, sb,
                                               nullptr, nullptr, hA, N);
    // layer 2: hA -> hA (residual + silu)
    gemm_qkvs<<<gemm_grid, 256, 0, stream>>>(hA, W[1][0], B[1][0], W[1][1], B[1][1],
                                             W[1][2], B[1][2], W[1][3], B[1][3],
                                             q, k, v, sb, N);
    edge_scores<<<edge_grid, 256, 0, stream>>>(q, k, ei, csr_pos, scores, E, flag);
    node_agg<2><<<node_grid, 256, 0, stream>>>(scores, csr_src, offsets, v, sb,
                                               hA, nullptr, hA, N);
    // layer 3: hA -> out, + 0.1*z
    gemm_qkvs<<<gemm_grid, 256, 0, stream>>>(hA, W[2][0], B[2][0], W[2][1], B[2][1],
                                             W[2][2], B[2][2], W[2][3], B[2][3],
                                             q, k, v, sb, N);
    edge_scores<<<edge_grid, 256, 0, stream>>>(q, k, ei, csr_pos, scores, E, flag);
    node_agg<3><<<node_grid, 256, 0, stream>>>(scores, csr_src, offsets, v, sb,
                                               nullptr, z, outp, N);
}